// Round 10
// baseline (350.177 us; speedup 1.0000x reference)
//
#include <hip/hip_runtime.h>

// BiLSTM: LSTM(B=2048,T=256,F=H=128) + linear head, fused, one block/CU.
// Round 10: PRODUCER/CONSUMER WAVE SPECIALIZATION. 16 waves (1024 thr):
// waves 0-7 = x-engines (hold only w_ih frags, compute gX = bias + x*w_ih
// one group ahead, write f32 D-fragments to LDS); waves 8-15 = h-engines
// (hold only w_hh frags, seed MFMA C directly from LDS gX fragment, run
// the recurrence + gates + h-exchange). Per-wave regs ~halve -> 4 waves/
// SIMD; x-wave work fills the h-waves' serial latency phases.

typedef __attribute__((ext_vector_type(8))) short short8;
typedef __attribute__((ext_vector_type(4))) float f32x4;
typedef __attribute__((ext_vector_type(2))) float f32x2;

#define T_STEPS 256
#define L2E 1.4426950408889634f

__device__ __forceinline__ unsigned int cvt_pk_bf16(float lo, float hi) {
    unsigned int r;
    asm volatile("v_cvt_pk_bf16_f32 %0, %1, %2" : "=v"(r) : "v"(lo), "v"(hi));
    return r;
}
__device__ __forceinline__ unsigned short f2bf(float f) {
    unsigned int u = __builtin_bit_cast(unsigned int, f);
    u += 0x7fffu + ((u >> 16) & 1u);   // RNE
    return (unsigned short)(u >> 16);
}
__device__ __forceinline__ float rcp_fast(float x) { return __builtin_amdgcn_rcpf(x); }
__device__ __forceinline__ float exp2f_fast(float x) { return __builtin_amdgcn_exp2f(x); }

__device__ __forceinline__ short8 pack8(const f32x4 a, const f32x4 b) {
    short8 v;
    v[0] = (short)f2bf(a[0]); v[1] = (short)f2bf(a[1]);
    v[2] = (short)f2bf(a[2]); v[3] = (short)f2bf(a[3]);
    v[4] = (short)f2bf(b[0]); v[5] = (short)f2bf(b[1]);
    v[6] = (short)f2bf(b[2]); v[7] = (short)f2bf(b[3]);
    return v;
}

// barrier draining LDS only; VMEM prefetches stay in flight
#define LBAR() asm volatile("s_waitcnt lgkmcnt(0)\n\ts_barrier" ::: "memory")

#define MFMA16(A, B, C) __builtin_amdgcn_mfma_f32_16x16x32_bf16((A), (B), (C), 0, 0, 0)

// gates from ch_[n][R]; 5 exp + 2 rcp per element
#define GATE(R, CS, WL, AJ, HO)                                                \
  { float gi = ch_[0][R];                                                      \
    float gf = ch_[1][R];                                                      \
    float gg = ch_[2][R];                                                      \
    float go = ch_[3][R];                                                      \
    float ef = exp2f_fast(gf * L2E);                                           \
    float ei = exp2f_fast(gi * L2E);                                           \
    float eg = exp2f_fast(gg * (2.f * L2E));                                   \
    float Fq = ef + 1.f, Iq = ei + 1.f, Gq = eg + 1.f;                         \
    float pq = Iq * Gq;                                                        \
    float Rq = rcp_fast(Fq * pq);                                              \
    float cq = __builtin_fmaf(ef * pq, (CS), (ei * Fq) * (eg - 1.f)) * Rq;     \
    (CS) = cq;                                                                 \
    float ccq = fminf(fmaxf(cq, -15.f), 15.f);                                 \
    float eo = exp2f_fast(go * L2E);                                           \
    float ec = exp2f_fast(ccq * (2.f * L2E));                                  \
    float oh = (eo * (ec - 1.f)) * rcp_fast((eo + 1.f) * (ec + 1.f));          \
    (AJ) = __builtin_fmaf(oh, (WL), (AJ));                                     \
    (HO) = oh; }

// h-engine one step: read hbuf[RP], seed from gXbuf[P], MFMA, gates for
// step-parity S (rows S and 2+S), write hbuf[WP]
#define HSTEP(RP, WP, P, S, WLS)                                               \
  { short8 af_[4];                                                             \
    f32x4 ch_[4];                                                              \
    _Pragma("unroll")                                                          \
    for (int kt = 0; kt < 4; ++kt)                                             \
      af_[kt] = *reinterpret_cast<const short8*>(&hbuf[RP][hridx[kt]]);        \
    _Pragma("unroll")                                                          \
    for (int n = 0; n < 4; ++n)                                                \
      ch_[n] = *reinterpret_cast<const f32x4*>(&gXbuf[P][n][w8][goff]);        \
    _Pragma("unroll")                                                          \
    for (int kt = 0; kt < 4; ++kt)                                             \
      _Pragma("unroll")                                                        \
      for (int n = 0; n < 4; ++n)                                              \
        ch_[n] = MFMA16(af_[kt], bq[kt][n], ch_[n]);                           \
    float h0_, h1_;                                                            \
    GATE((S), cst0, (WLS), acc0, h0_);                                         \
    GATE((2 + (S)), cst1, (WLS), acc1, h1_);                                   \
    unsigned int hpk_ = cvt_pk_bf16(h0_, h1_);                                 \
    hbuf[WP][hwidx0] = (unsigned short)hpk_;                                   \
    hbuf[WP][hwidx1] = (unsigned short)(hpk_ >> 16); }

// one 2-step group; P = group parity ((T0>>1)&1)
#define GROUPP(T0, P)                                                          \
  {  /* ===== window A ===== */                                                \
    if (xw) {  /* gX for group g+1 from xbuf[P^1] */                           \
      short8 af_[4];                                                           \
      _Pragma("unroll")                                                        \
      for (int kt = 0; kt < 4; ++kt)                                           \
        af_[kt] = *reinterpret_cast<const short8*>(&xbuf[(P) ^ 1][xridx[kt]]); \
      _Pragma("unroll")                                                        \
      for (int n = 0; n < 4; ++n)                                              \
        gx[n] = (f32x4){bias[n], bias[n], bias[n], bias[n]};                   \
      _Pragma("unroll")                                                        \
      for (int kt = 0; kt < 4; ++kt)                                           \
        _Pragma("unroll")                                                      \
        for (int n = 0; n < 4; ++n)                                            \
          gx[n] = MFMA16(af_[kt], bq[kt][n], gx[n]);                           \
      const int tt = ((T0) + 4 < T_STEPS) ? (T0) + 4 : 0;                      \
      nx0 = *reinterpret_cast<const f32x2*>(xrow + (size_t)tt * 128);          \
      nx1 = *reinterpret_cast<const f32x2*>(xrow + (size_t)(tt + 1) * 128);    \
    } else {                                                                   \
      HSTEP(0, 1, (P), 0, wlA);                                                \
      const int tw = ((T0) + 2 < T_STEPS) ? (T0) + 2 : 0;                      \
      wlN0 = w_lin[tw * 128 + hid];                                            \
      wlN1 = w_lin[(tw + 1) * 128 + hid];                                      \
    }                                                                          \
    LBAR();                                                                    \
    /* ===== window B ===== */                                                 \
    if (xw) {  /* publish gX(g+1); stage x for group g+2 */                    \
      _Pragma("unroll")                                                        \
      for (int n = 0; n < 4; ++n)                                              \
        *reinterpret_cast<f32x4*>(&gXbuf[(P) ^ 1][n][w8][goff]) = gx[n];       \
      *reinterpret_cast<unsigned int*>(&xbuf[P][xw0]) =                        \
          cvt_pk_bf16(nx0[0], nx0[1]);                                         \
      *reinterpret_cast<unsigned int*>(&xbuf[P][xw1]) =                        \
          cvt_pk_bf16(nx1[0], nx1[1]);                                         \
    } else {                                                                   \
      HSTEP(1, 0, (P), 1, wlB);                                                \
      wlA = wlN0; wlB = wlN1;                                                  \
    }                                                                          \
    LBAR();                                                                    \
  }

__global__ __launch_bounds__(1024, 4) void lstm_fused_kernel(
    const float* __restrict__ x,     // [2048,256,128]
    const float* __restrict__ w_ih,  // [512,128]
    const float* __restrict__ w_hh,  // [512,128]
    const float* __restrict__ b_ih,  // [512]
    const float* __restrict__ b_hh,  // [512]
    const float* __restrict__ w_lin, // [1, 256*128]
    const float* __restrict__ b_lin, // [1]
    float* __restrict__ out)         // [2048]
{
    // xbuf: bf16 [16 rows][128], row = batch*2 + step-in-group, ^((r&7)<<3)
    // hbuf: bf16 [parity][8 rows][128], row = batch, ^(row<<3)
    // gXbuf: f32 D-fragments [par][gate n][x-wave][col*16 + (4kq ^ swz)]
    __shared__ __align__(16) unsigned short xbuf[2][16 * 128];
    __shared__ __align__(16) unsigned short hbuf[2][8 * 128];
    __shared__ __align__(16) float gXbuf[2][4][8][256];
    __shared__ float redout[8][8];

    const int tid  = threadIdx.x;
    const int wave = tid >> 6;        // 0..15
    const int lane = tid & 63;
    const int c16  = lane & 15;
    const int kq   = lane >> 4;       // 0..3
    const int row0 = blockIdx.x * 8;
    const bool xw  = (wave < 8);      // x-engine?
    const int w8   = wave & 7;
    const int hid  = w8 * 16 + c16;   // h-wave's owned column

    // ---- weights: x-waves load w_ih frags, h-waves load w_hh frags ----
    short8 bq[4][4];
#pragma unroll
    for (int kt = 0; kt < 4; ++kt) {
#pragma unroll
        for (int n = 0; n < 4; ++n) {
            const int G  = n * 128 + w8 * 16 + c16;
            const int k0 = kt * 32 + kq * 8;
            const float* src = (xw ? w_ih : w_hh) + G * 128 + k0;
            f32x4 lo = *reinterpret_cast<const f32x4*>(src);
            f32x4 hi = *reinterpret_cast<const f32x4*>(src + 4);
            bq[kt][n] = pack8(lo, hi);
        }
    }
    float bias[4] = {0.f, 0.f, 0.f, 0.f};
    if (xw) {
#pragma unroll
        for (int n = 0; n < 4; ++n) {
            const int G = n * 128 + w8 * 16 + c16;
            bias[n] = b_ih[G] + b_hh[G];
        }
    }

    // A-frag indices
    int xridx[4], hridx[4];
    const int hcr = c16 >> 1;
#pragma unroll
    for (int kt = 0; kt < 4; ++kt) {
        xridx[kt] = (c16 * 128 + kt * 32 + kq * 8) ^ ((c16 & 7) << 3);
        hridx[kt] = hcr * 128 + ((kt * 32 + kq * 8) ^ (hcr << 3));
    }
    // gX fragment offset (f32 units) within [n][w8] block; 2-way banked
    const int goff = c16 * 16 + ((4 * kq) ^ (((c16 >> 1) & 3) << 2));

    // x staging: x-wave w8 owns batch w8 -> xbuf rows 2w8 (s=0), 2w8+1 (s=1)
    const int xr0 = w8 * 2, xr1 = w8 * 2 + 1;
    const int xw0 = (xr0 * 128 + lane * 2) ^ ((xr0 & 7) << 3);
    const int xw1 = (xr1 * 128 + lane * 2) ^ ((xr1 & 7) << 3);
    const float* xrow = x + (size_t)(row0 + w8) * T_STEPS * 128 + lane * 2;

    // h write: h-wave lane (c16,kq) owns batches 2kq+j at col hid
    const int hwidx0 = ((2 * kq + 0) * 128 + hid) ^ ((2 * kq + 0) << 3);
    const int hwidx1 = ((2 * kq + 1) * 128 + hid) ^ ((2 * kq + 1) << 3);

    // ---- prologue ----
    if (xw) {  // stage x(t0,t1)->xbuf[0], x(t2,t3)->xbuf[1]
        f32x2 v0 = *reinterpret_cast<const f32x2*>(xrow);
        f32x2 v1 = *reinterpret_cast<const f32x2*>(xrow + 128);
        f32x2 v2 = *reinterpret_cast<const f32x2*>(xrow + 2 * 128);
        f32x2 v3 = *reinterpret_cast<const f32x2*>(xrow + 3 * 128);
        *reinterpret_cast<unsigned int*>(&xbuf[0][xw0]) = cvt_pk_bf16(v0[0], v0[1]);
        *reinterpret_cast<unsigned int*>(&xbuf[0][xw1]) = cvt_pk_bf16(v1[0], v1[1]);
        *reinterpret_cast<unsigned int*>(&xbuf[1][xw0]) = cvt_pk_bf16(v2[0], v2[1]);
        *reinterpret_cast<unsigned int*>(&xbuf[1][xw1]) = cvt_pk_bf16(v3[0], v3[1]);
    } else {   // zero hbuf (h0 = 0): 4KB = 1024 dwords, 512 h-lanes x 2
        reinterpret_cast<unsigned long long*>(hbuf)[tid - 512] = 0ull;
    }
    __syncthreads();

    f32x4 gx[4];
    if (xw) {  // gX(group 0) from xbuf[0] -> gXbuf[0]
        short8 af_[4];
#pragma unroll
        for (int kt = 0; kt < 4; ++kt)
            af_[kt] = *reinterpret_cast<const short8*>(&xbuf[0][xridx[kt]]);
#pragma unroll
        for (int n = 0; n < 4; ++n)
            gx[n] = (f32x4){bias[n], bias[n], bias[n], bias[n]};
#pragma unroll
        for (int kt = 0; kt < 4; ++kt)
#pragma unroll
            for (int n = 0; n < 4; ++n)
                gx[n] = MFMA16(af_[kt], bq[kt][n], gx[n]);
#pragma unroll
        for (int n = 0; n < 4; ++n)
            *reinterpret_cast<f32x4*>(&gXbuf[0][n][w8][goff]) = gx[n];
    }

    float cst0 = 0.f, cst1 = 0.f;
    float acc0 = 0.f, acc1 = 0.f;
    float wlA = 0.f, wlB = 0.f, wlN0 = 0.f, wlN1 = 0.f;
    if (!xw) { wlA = w_lin[hid]; wlB = w_lin[128 + hid]; }
    f32x2 nx0 = {0.f, 0.f}, nx1 = {0.f, 0.f};

    __syncthreads();

    for (int t = 0; t < T_STEPS; t += 4) {
        GROUPP(t, 0);
        GROUPP(t + 2, 1);
    }

    // ---- reduction: h-waves only hold acc ----
    if (!xw) {
#pragma unroll
        for (int r = 0; r < 2; ++r) {
            float v = (r == 0) ? acc0 : acc1;
            v += __shfl_xor(v, 1);
            v += __shfl_xor(v, 2);
            v += __shfl_xor(v, 4);
            v += __shfl_xor(v, 8);
            if (c16 == 0) redout[w8][2 * kq + r] = v;  // batch 2kq+r
        }
    }
    __syncthreads();
    if (tid < 8) {
        float s = b_lin[0];
#pragma unroll
        for (int w = 0; w < 8; ++w) s += redout[w][tid];
        out[row0 + tid] = s;
    }
}

extern "C" void kernel_launch(void* const* d_in, const int* in_sizes, int n_in,
                              void* d_out, int out_size, void* d_ws, size_t ws_size,
                              hipStream_t stream) {
    const float* x     = (const float*)d_in[0];
    const float* w_ih  = (const float*)d_in[1];
    const float* w_hh  = (const float*)d_in[2];
    const float* b_ih  = (const float*)d_in[3];
    const float* b_hh  = (const float*)d_in[4];
    const float* w_lin = (const float*)d_in[5];
    const float* b_lin = (const float*)d_in[6];
    float* out = (float*)d_out;

    lstm_fused_kernel<<<256, 1024, 0, stream>>>(x, w_ih, w_hh, b_ih, b_hh, w_lin, b_lin, out);
}